// Round 8
// baseline (1629.698 us; speedup 1.0000x reference)
//
#include <hip/hip_runtime.h>
#include <hip/hip_bf16.h>

#define E_EDGES 131072
#define NNODES  8192
#define NB      16384   // N_NODES * BATCH rows
#define HID     256
#define EDIM    64
#define MLPH    512
#define OUTD    128
#define NIT     3

typedef short s16x4 __attribute__((ext_vector_type(4)));
typedef short s16x8 __attribute__((ext_vector_type(8)));
typedef float f32x4 __attribute__((ext_vector_type(4)));

__device__ __forceinline__ short f2bf(float f){
  unsigned int x = __builtin_bit_cast(unsigned int, f);
  x += 0x7fffu + ((x >> 16) & 1u);          // RNE
  return (short)(x >> 16);
}
__device__ __forceinline__ float bf2f(short s){
  unsigned int x = ((unsigned int)(unsigned short)s) << 16;
  return __builtin_bit_cast(float, x);
}
__device__ __forceinline__ void gload_lds16(const void* g, void* l){
  __builtin_amdgcn_global_load_lds(
      (const __attribute__((address_space(1))) void*)g,
      (__attribute__((address_space(3))) void*)l, 16, 0, 0);
}
#define MFMA16(a,b,c) __builtin_amdgcn_mfma_f32_16x16x32_bf16((a),(b),(c),0,0,0)

// ===========================================================================
// edge_fused v3 — BARRIER-FREE, wave-private. Block = 16 nodes, 512 thr.
// Wave w owns output cols w*64..w*64+63 end-to-end:
//   per 32-CSR-position window:
//     - lanes load ceid directly (coalesced), gather 8x16B ebf A-frags
//     - 32 MFMAs -> wave-private T-slice Tw[64 rows][64 cols] (bf16, XOR swz)
//     - accum (same wave): lane (sr=l&31, half=l>>5) owns 32 cols of S-row sr;
//       for its node's edges in window: acc += relu(Tw[er] + P1+b1 (+P2[src]))
// No __syncthreads anywhere; same-wave LDS WAR ordered by compiler lgkmcnt.
// 16 independent waves/CU hide gather latency.
// ===========================================================================
template<bool USE_P>
__global__ __launch_bounds__(512, 4)
void edge_fused(const short* __restrict__ ebf, const short* __restrict__ BtE,
                const short* __restrict__ P, const int* __restrict__ ceid,
                const int* __restrict__ csrc, const int* __restrict__ rs,
                const float* __restrict__ b1, short* __restrict__ S)
{
  __shared__ __align__(16) short T[8][64 * 64];   // 8 KB per wave, 64 KB total

  const int tid = threadIdx.x;
  const int w  = tid >> 6, l = tid & 63;
  const int lr = l & 15, lg = l >> 4;
  const int node0 = blockIdx.x * 16;
  const int p0 = rs[node0], p1 = rs[node0 + 16];
  short* Tw = &T[w][0];

  // ---- B-operand: wave's 64-col BtE slice in registers (K=64) ----
  s16x8 Bf0[4], Bf1[4];
#pragma unroll
  for (int nf = 0; nf < 4; ++nf){
    const short* bp = BtE + (size_t)(w * 64 + nf * 16 + lr) * 64 + lg * 8;
    Bf0[nf] = *(const s16x8*)bp;
    Bf1[nf] = *(const s16x8*)(bp + 32);
  }

  // ---- accum ownership: S-row sr, 32 cols at c0 ----
  const int sr  = l & 31;
  const int hlf = l >> 5;
  const int nd  = node0 + (sr >> 1);
  const int sb  = sr & 1;
  const int c0  = w * 64 + hlf * 32;        // global col base
  const int ps  = rs[nd], pe = rs[nd + 1];

  float acc[32];
#pragma unroll
  for (int c = 0; c < 32; ++c) acc[c] = 0.f;

  // p1c packed bf16 (8 VGPR): bf16(b1 + P1[nd])   [b1 only if !USE_P]
  s16x8 p1cb[4];
#pragma unroll
  for (int u = 0; u < 4; ++u){
    s16x8 pv = USE_P ? *(const s16x8*)(P + (size_t)(nd * 2 + sb) * 1024 + c0 + u * 8)
                     : (s16x8){0,0,0,0,0,0,0,0};
#pragma unroll
    for (int j = 0; j < 8; ++j)
      p1cb[u][j] = f2bf(b1[c0 + u * 8 + j] + (USE_P ? bf2f(pv[j]) : 0.f));
  }

  const int nwin = (p1 - p0 + 31) >> 5;

  for (int t = 0; t < nwin; ++t){
    const int pw0 = p0 + t * 32;

    // ---- A-gather: eids direct from global (coalesced 32B per 16 lanes) ----
    int eidv[4];
#pragma unroll
    for (int mf = 0; mf < 4; ++mf){
      int pp = pw0 + mf * 8 + (lr >> 1);
      if (pp > E_EDGES - 1) pp = E_EDGES - 1;
      eidv[mf] = ceid[pp];
    }
    s16x8 A0[4], A1[4];
#pragma unroll
    for (int mf = 0; mf < 4; ++mf){
      const short* ap = ebf + ((size_t)eidv[mf] * 2 + (lr & 1)) * 64 + lg * 8;
      A0[mf] = *(const s16x8*)ap;
      A1[mf] = *(const s16x8*)(ap + 32);
    }

    // ---- MFMA -> wave-private T slice (bf16, XOR-swizzled rows) ----
#pragma unroll
    for (int mf = 0; mf < 4; ++mf){
      f32x4 cf[4];
#pragma unroll
      for (int nf = 0; nf < 4; ++nf){
        cf[nf] = (f32x4){0.f,0.f,0.f,0.f};
        cf[nf] = MFMA16(A0[mf], Bf0[nf], cf[nf]);
        cf[nf] = MFMA16(A1[mf], Bf1[nf], cf[nf]);
      }
#pragma unroll
      for (int nf = 0; nf < 4; ++nf){
        int cl = nf * 16 + lr;              // col within wave slice
#pragma unroll
        for (int r = 0; r < 4; ++r){
          int row = mf * 16 + lg * 4 + r;
          Tw[row * 64 + (cl ^ ((row & 7) << 3))] = f2bf(cf[nf][r]);
        }
      }
    }

    // ---- accum: this lane's node-edges within the window (same wave) ----
    int pa = ps > pw0 ? ps : pw0;
    int pb = pe < pw0 + 32 ? pe : pw0 + 32;
    for (int p = pa; p < pb; ++p){
      int er = (p - pw0) * 2 + sb;
      int rx = (er & 7) << 3;
      const short* trow = Tw + er * 64;
      if (USE_P){
        const short* p2r = P + ((size_t)csrc[p] * 2 + sb) * 1024 + 512 + c0;
#pragma unroll
        for (int u = 0; u < 4; ++u){
          s16x8 tv = *(const s16x8*)(trow + ((hlf * 32 + u * 8) ^ rx));
          s16x8 pv = *(const s16x8*)(p2r + u * 8);
#pragma unroll
          for (int j = 0; j < 8; ++j){
            float v = bf2f(tv[j]) + bf2f(pv[j]) + bf2f(p1cb[u][j]);
            acc[u * 8 + j] += fmaxf(v, 0.f);
          }
        }
      } else {
#pragma unroll
        for (int u = 0; u < 4; ++u){
          s16x8 tv = *(const s16x8*)(trow + ((hlf * 32 + u * 8) ^ rx));
#pragma unroll
          for (int j = 0; j < 8; ++j){
            float v = bf2f(tv[j]) + bf2f(p1cb[u][j]);
            acc[u * 8 + j] += fmaxf(v, 0.f);
          }
        }
      }
    }
  }

  // ---- write S (bf16); deg-0 nodes write zeros (matches segment_sum) ----
#pragma unroll
  for (int u = 0; u < 4; ++u){
    s16x8 o;
#pragma unroll
    for (int j = 0; j < 8; ++j) o[j] = f2bf(acc[u * 8 + j]);
    *(s16x8*)(S + (size_t)(node0 * 2 + sr) * 512 + c0 + u * 8) = o;
  }
}

// ===========================================================================
// node_update: block = 64 rows, 512 threads (8 waves = 2 row x 4 col),
// 256 blocks. LDS Ms/Xs (64 KB). S A-frags direct from global (L2/L3-hot).
// Phases: A (m update), B+C (Gr,Gz), e1, D (Gw), e2, E (P) / readout.
// ===========================================================================
template<int PH>
__global__ __launch_bounds__(512, 2)
void node_update(const short* __restrict__ S, short* __restrict__ Pout,
                 float* __restrict__ m, float* __restrict__ h,
                 float* __restrict__ g,
                 const short* __restrict__ BtW2, const short* __restrict__ BtRZ,
                 const short* __restrict__ BtHW, const short* __restrict__ BtP,
                 const int* __restrict__ deg, const float* __restrict__ b2,
                 const float* __restrict__ br, const float* __restrict__ bz,
                 const float* __restrict__ bh)
{
  __shared__ __align__(16) char lds[65536];
  short* Ms = (short*)lds;              // [64][256] bf16 swizzled
  short* Xs = (short*)(lds + 32768);    // [64][256] bf16 swizzled
  float* Hf = (float*)lds;              // [64][256] f32 overlay (PH2 only)

  const int tid = threadIdx.x;
  const int w = tid >> 6, l = tid & 63;
  const int lr = l & 15, lg = l >> 4;
  const int wrow = w >> 2, wcol = w & 3;
  const int rb = wrow * 32;
  const int grow0 = blockIdx.x * 64;

  auto rd256 = [&](int row, int c){ return row * 256 + (c ^ ((row & 7) << 3)); };

  // ---- h into regs, acc init = m + deg*b2; Xs <- bf16(h) ----
  f32x4 hv[2][4], acc[2][4];
#pragma unroll
  for (int i = 0; i < 2; ++i)
#pragma unroll
    for (int j = 0; j < 4; ++j)
#pragma unroll
      for (int r = 0; r < 4; ++r){
        int rl = rb + i*16 + lg*4 + r, colp = wcol*64 + j*16 + lr;
        size_t gi = (size_t)(grow0 + rl) * 256 + colp;
        float base = (float)deg[(grow0 + rl) >> 1] * b2[colp];
        if (PH > 0){ base += m[gi]; hv[i][j][r] = h[gi]; }
        else hv[i][j][r] = 0.f;
        acc[i][j][r] = base;
      }
  if (PH > 0){
#pragma unroll
    for (int i = 0; i < 2; ++i)
#pragma unroll
      for (int j = 0; j < 4; ++j)
#pragma unroll
        for (int r = 0; r < 4; ++r){
          int rl = rb + i*16 + lg*4 + r, colp = wcol*64 + j*16 + lr;
          Xs[rd256(rl, colp)] = f2bf(hv[i][j][r]);
        }
  }

  // ---- Phase A: acc += S @ W2 (K=512), A-frags direct from global ----
#pragma unroll 4
  for (int c = 0; c < 16; ++c){
    s16x8 a0 = *(const s16x8*)(S + (size_t)(grow0 + rb + lr)      * 512 + c*32 + lg*8);
    s16x8 a1 = *(const s16x8*)(S + (size_t)(grow0 + rb + 16 + lr) * 512 + c*32 + lg*8);
#pragma unroll
    for (int j = 0; j < 4; ++j){
      s16x8 bb = *(const s16x8*)(BtW2 + (size_t)(wcol*64 + j*16 + lr) * 512 + c*32 + lg*8);
      acc[0][j] = MFMA16(a0, bb, acc[0][j]);
      acc[1][j] = MFMA16(a1, bb, acc[1][j]);
    }
  }
#pragma unroll
  for (int i = 0; i < 2; ++i)
#pragma unroll
    for (int j = 0; j < 4; ++j)
#pragma unroll
      for (int r = 0; r < 4; ++r){
        int rl = rb + i*16 + lg*4 + r, colp = wcol*64 + j*16 + lr;
        float v = acc[i][j][r];
        if (PH < 2) m[(size_t)(grow0 + rl) * 256 + colp] = v;
        Ms[rd256(rl, colp)] = f2bf(v);
      }
  __syncthreads();                         // Ms(m_bf) + Xs(hb) visible

  // ---- Phase B+C: Gr, Gz in one A-pass ----
  f32x4 Gr[2][4], Gz[2][4];
#pragma unroll
  for (int i = 0; i < 2; ++i)
#pragma unroll
    for (int j = 0; j < 4; ++j){ Gr[i][j] = (f32x4){0.f,0.f,0.f,0.f}; Gz[i][j] = (f32x4){0.f,0.f,0.f,0.f}; }

  auto gemmRZ = [&](const short* Ab, int koff){
#pragma unroll 2
    for (int c = 0; c < 8; ++c){
      s16x8 a0 = *(const s16x8*)(Ab + rd256(rb + lr,      c*32 + lg*8));
      s16x8 a1 = *(const s16x8*)(Ab + rd256(rb + 16 + lr, c*32 + lg*8));
#pragma unroll
      for (int j = 0; j < 4; ++j){
        int colr = wcol*64 + j*16 + lr;
        s16x8 b_r = *(const s16x8*)(BtRZ + (size_t)colr         * 512 + koff + c*32 + lg*8);
        s16x8 b_z = *(const s16x8*)(BtRZ + (size_t)(256 + colr) * 512 + koff + c*32 + lg*8);
        Gr[0][j] = MFMA16(a0, b_r, Gr[0][j]);
        Gr[1][j] = MFMA16(a1, b_r, Gr[1][j]);
        Gz[0][j] = MFMA16(a0, b_z, Gz[0][j]);
        Gz[1][j] = MFMA16(a1, b_z, Gz[1][j]);
      }
    }
  };
  gemmRZ(Ms, 0);
  if (PH > 0) gemmRZ(Xs, 256);

  // ---- e1: r, z; Xs <- bf16(r*h) ----
  f32x4 zz[2][4];
#pragma unroll
  for (int i = 0; i < 2; ++i)
#pragma unroll
    for (int j = 0; j < 4; ++j)
#pragma unroll
      for (int r = 0; r < 4; ++r){
        int colp = wcol*64 + j*16 + lr;
        zz[i][j][r] = 1.f / (1.f + __expf(-(Gz[i][j][r] + bz[colp])));
      }
  if (PH > 0){
    __syncthreads();                       // B/C's Xs(hb) reads done
#pragma unroll
    for (int i = 0; i < 2; ++i)
#pragma unroll
      for (int j = 0; j < 4; ++j)
#pragma unroll
        for (int r = 0; r < 4; ++r){
          int rl = rb + i*16 + lg*4 + r, colp = wcol*64 + j*16 + lr;
          float rr = 1.f / (1.f + __expf(-(Gr[i][j][r] + br[colp])));
          Xs[rd256(rl, colp)] = f2bf(rr * hv[i][j][r]);
        }
    __syncthreads();                       // Xs(rh) visible
  }

  // ---- Phase D: Gw = [m|rh] @ BtHW ----
  f32x4 Gw[2][4];
#pragma unroll
  for (int i = 0; i < 2; ++i)
#pragma unroll
    for (int j = 0; j < 4; ++j) Gw[i][j] = (f32x4){0.f,0.f,0.f,0.f};
  auto gemmHW = [&](const short* Ab, int koff){
#pragma unroll 2
    for (int c = 0; c < 8; ++c){
      s16x8 a0 = *(const s16x8*)(Ab + rd256(rb + lr,      c*32 + lg*8));
      s16x8 a1 = *(const s16x8*)(Ab + rd256(rb + 16 + lr, c*32 + lg*8));
#pragma unroll
      for (int j = 0; j < 4; ++j){
        s16x8 bb = *(const s16x8*)(BtHW + (size_t)(wcol*64 + j*16 + lr) * 512 + koff + c*32 + lg*8);
        Gw[0][j] = MFMA16(a0, bb, Gw[0][j]);
        Gw[1][j] = MFMA16(a1, bb, Gw[1][j]);
      }
    }
  };
  gemmHW(Ms, 0);
  if (PH > 0) gemmHW(Xs, 256);
  __syncthreads();                         // D's Ms/Xs reads done

  // ---- e2: h' ----
#pragma unroll
  for (int i = 0; i < 2; ++i)
#pragma unroll
    for (int j = 0; j < 4; ++j)
#pragma unroll
      for (int r = 0; r < 4; ++r){
        int rl = rb + i*16 + lg*4 + r, colp = wcol*64 + j*16 + lr;
        float ht = tanhf(Gw[i][j][r] + bh[colp]);
        float z  = zz[i][j][r];
        float hn = (1.f - z) * hv[i][j][r] + z * ht;
        if (PH < 2){
          h[(size_t)(grow0 + rl) * 256 + colp] = hn;
          Ms[rd256(rl, colp)] = f2bf(hn);
        } else {
          Hf[rl * 256 + colp] = hn;
        }
      }
  __syncthreads();                         // Ms(h') / Hf visible

  if (PH < 2){
    // ---- Phase E: P = h' @ BtP, 4 panels of 256 cols ----
    for (int pn = 0; pn < 4; ++pn){
      f32x4 pa0[4], pa1[4];
#pragma unroll
      for (int j = 0; j < 4; ++j){ pa0[j] = (f32x4){0.f,0.f,0.f,0.f}; pa1[j] = (f32x4){0.f,0.f,0.f,0.f}; }
#pragma unroll 2
      for (int c = 0; c < 8; ++c){
        s16x8 a0 = *(const s16x8*)(Ms + rd256(rb + lr,      c*32 + lg*8));
        s16x8 a1 = *(const s16x8*)(Ms + rd256(rb + 16 + lr, c*32 + lg*8));
#pragma unroll
        for (int j = 0; j < 4; ++j){
          s16x8 bb = *(const s16x8*)(BtP + (size_t)(pn*256 + wcol*64 + j*16 + lr) * 256 + c*32 + lg*8);
          pa0[j] = MFMA16(a0, bb, pa0[j]);
          pa1[j] = MFMA16(a1, bb, pa1[j]);
        }
      }
#pragma unroll
      for (int j = 0; j < 4; ++j)
#pragma unroll
        for (int r = 0; r < 4; ++r){
          int colp = wcol*64 + j*16 + lr;
          Pout[(size_t)(grow0 + rb + lg*4 + r)      * 1024 + pn*256 + colp] = f2bf(pa0[j][r]);
          Pout[(size_t)(grow0 + rb + 16 + lg*4 + r) * 1024 + pn*256 + colp] = f2bf(pa1[j][r]);
        }
    }
  } else {
    // ---- readout partial over the block's 64 rows ----
    int col = tid & 255, pb = tid >> 8;    // pb = batch parity
    float s = 0.f;
#pragma unroll
    for (int rr = 0; rr < 32; ++rr)
      s += Hf[(2*rr + pb) * 256 + col];
    atomicAdd(&g[pb * 256 + col], s);
  }
}

// --------------------------- ef -> bf16 conversion -------------------------
__global__ __launch_bounds__(256)
void cvt_ef(const float* __restrict__ ef, short* __restrict__ ebf){
  size_t i = (size_t)(blockIdx.x * 256 + threadIdx.x) * 8;
  f32x4 f0 = *(const f32x4*)(ef + i);
  f32x4 f1 = *(const f32x4*)(ef + i + 4);
  s16x8 o;
  o[0]=f2bf(f0[0]); o[1]=f2bf(f0[1]); o[2]=f2bf(f0[2]); o[3]=f2bf(f0[3]);
  o[4]=f2bf(f1[0]); o[5]=f2bf(f1[1]); o[6]=f2bf(f1[2]); o[7]=f2bf(f1[3]);
  *(s16x8*)(ebf + i) = o;
}

// ------------------------------- CSR build ---------------------------------
__global__ void count_kernel(const int* __restrict__ edst, int* __restrict__ counts){
  int e = blockIdx.x * 256 + threadIdx.x;
  if (e < E_EDGES) atomicAdd(&counts[edst[e]], 1);
}
__global__ void scan_kernel(const int* __restrict__ counts, int* __restrict__ row_start,
                            int* __restrict__ cursor){
  __shared__ int sums[1024];
  int t = threadIdx.x;
  int base = t * 8;
  int loc[8]; int s = 0;
#pragma unroll
  for (int i = 0; i < 8; ++i){ loc[i] = s; s += counts[base + i]; }
  sums[t] = s;
  __syncthreads();
  for (int o = 1; o < 1024; o <<= 1){
    int v = sums[t];
    int u = (t >= o) ? sums[t - o] : 0;
    __syncthreads();
    sums[t] = v + u;
    __syncthreads();
  }
  int excl = (t == 0) ? 0 : sums[t - 1];
#pragma unroll
  for (int i = 0; i < 8; ++i){ int v = excl + loc[i]; row_start[base + i] = v; cursor[base + i] = v; }
  if (t == 1023) row_start[NNODES] = sums[1023];
}
__global__ void fill_kernel(const int* __restrict__ edst, const int* __restrict__ esrc,
                            int* __restrict__ cursor, int* __restrict__ csr_eid,
                            int* __restrict__ csr_src){
  int e = blockIdx.x * 256 + threadIdx.x;
  if (e < E_EDGES){
    int pos = atomicAdd(&cursor[edst[e]], 1);
    csr_eid[pos] = e;
    csr_src[pos] = esrc[e];
  }
}

// --------------------------- weight repacking ------------------------------
// BtP [1024][256], BtE [512][64] (plain), BtW2 [256][512],
// BtRZ [512][512] (cols r|z, K = W|U), BtHW [256][512] (K = Wh|Uh)
__global__ void prep_weights(const float* __restrict__ W1, const float* __restrict__ W2,
                             const float* __restrict__ Wr, const float* __restrict__ Ur,
                             const float* __restrict__ Wz, const float* __restrict__ Uz,
                             const float* __restrict__ Wh, const float* __restrict__ Uh,
                             short* __restrict__ BtP, short* __restrict__ BtE,
                             short* __restrict__ BtW2, short* __restrict__ BtRZ,
                             short* __restrict__ BtHW)
{
  int id = blockIdx.x * 256 + threadIdx.x;
  if (id < 262144){                       // BtP
    int jj = id >> 8, k = id & 255;
    float v = (jj < 512) ? W1[(size_t)k * 512 + jj] : W1[(size_t)(256 + k) * 512 + (jj - 512)];
    BtP[id] = f2bf(v);
  } else if (id < 294912){                // BtE (plain [512][64])
    int i2 = id - 262144; int jj = i2 >> 6, c = i2 & 63;
    BtE[i2] = f2bf(W1[(size_t)(512 + c) * 512 + jj]);
  } else if (id < 425984){                // BtW2
    int i2 = id - 294912; int n = i2 >> 9, k = i2 & 511;
    BtW2[i2] = f2bf(W2[(size_t)k * 256 + n]);
  } else if (id < 688128){                // BtRZ
    int i2 = id - 425984; int col = i2 >> 9, k = i2 & 511;
    float v;
    if (col < 256) v = (k < 256) ? Wr[(size_t)k * 256 + col] : Ur[(size_t)(k - 256) * 256 + col];
    else { int c2 = col - 256; v = (k < 256) ? Wz[(size_t)k * 256 + c2] : Uz[(size_t)(k - 256) * 256 + c2]; }
    BtRZ[i2] = f2bf(v);
  } else if (id < 819200){                // BtHW
    int i2 = id - 688128; int col = i2 >> 9, k = i2 & 511;
    float v = (k < 256) ? Wh[(size_t)k * 256 + col] : Uh[(size_t)(k - 256) * 256 + col];
    BtHW[i2] = f2bf(v);
  }
}

// -------------------------------- readout ----------------------------------
__global__ __launch_bounds__(256)
void readout2(const float* __restrict__ g, const float* __restrict__ Wo,
              const float* __restrict__ bo, float* __restrict__ out){
  int t = threadIdx.x;
  int b = t >> 7, o = t & 127;
  float s = bo[o];
  for (int c = 0; c < 256; ++c) s += g[b * 256 + c] * Wo[c * 128 + o];
  out[b * 128 + o] = s;
}

// ===========================================================================
extern "C" void kernel_launch(void* const* d_in, const int* in_sizes, int n_in,
                              void* d_out, int out_size, void* d_ws, size_t ws_size,
                              hipStream_t stream)
{
  const float* ef  = (const float*)d_in[0];
  const float* W1  = (const float*)d_in[1];
  const float* b1  = (const float*)d_in[2];
  const float* W2  = (const float*)d_in[3];
  const float* b2  = (const float*)d_in[4];
  const float* Wr  = (const float*)d_in[5];
  const float* Ur  = (const float*)d_in[6];
  const float* br  = (const float*)d_in[7];
  const float* Wz  = (const float*)d_in[8];
  const float* Uz  = (const float*)d_in[9];
  const float* bz  = (const float*)d_in[10];
  const float* Wh  = (const float*)d_in[11];
  const float* Uh  = (const float*)d_in[12];
  const float* bh  = (const float*)d_in[13];
  const float* Wo  = (const float*)d_in[14];
  const float* bo  = (const float*)d_in[15];
  const int* esrc  = (const int*)d_in[16];
  const int* edst  = (const int*)d_in[17];

  char* base = (char*)d_ws;
  size_t off = 0;
  auto alloc = [&](size_t bytes) -> char* {
    off = (off + 255) & ~(size_t)255;
    char* p = base + off;
    off += bytes;
    return p;
  };
  float* h    = (float*)alloc((size_t)NB * 256 * 4);   // 16 MB
  float* m    = (float*)alloc((size_t)NB * 256 * 4);   // 16 MB
  short* P    = (short*)alloc((size_t)NB * 1024 * 2);  // 32 MB
  short* S    = (short*)alloc((size_t)NB * 512 * 2);   // 16 MB
  short* ebf  = (short*)alloc((size_t)E_EDGES * 2 * EDIM * 2);  // 33.5 MB
  short* BtP  = (short*)alloc(262144 * 2);
  short* BtE  = (short*)alloc(32768 * 2);
  short* BtW2 = (short*)alloc(131072 * 2);
  short* BtRZ = (short*)alloc(262144 * 2);
  short* BtHW = (short*)alloc(131072 * 2);
  int* counts = (int*)alloc(NNODES * 4);
  int* rs     = (int*)alloc((NNODES + 1) * 4);
  int* cursor = (int*)alloc(NNODES * 4);
  int* ceid   = (int*)alloc(E_EDGES * 4);
  int* csrc   = (int*)alloc(E_EDGES * 4);
  float* g    = (float*)alloc(512 * 4);
  // total ~120 MB << 256 MiB workspace

  dim3 blk(256);

  // ------------------------------- prep ----------------------------------
  hipMemsetAsync(g,  0, 512 * 4, stream);
  hipMemsetAsync(counts, 0, NNODES * 4, stream);
  prep_weights<<<3200, blk, 0, stream>>>(W1, W2, Wr, Ur, Wz, Uz, Wh, Uh,
                                         BtP, BtE, BtW2, BtRZ, BtHW);
  cvt_ef<<<(E_EDGES * 2 * EDIM) / (256 * 8), blk, 0, stream>>>(ef, ebf);
  count_kernel<<<512, blk, 0, stream>>>(edst, counts);
  scan_kernel<<<1, 1024, 0, stream>>>(counts, rs, cursor);
  fill_kernel<<<512, blk, 0, stream>>>(edst, esrc, cursor, ceid, csrc);

  // ----------------------------- iterations ------------------------------
  edge_fused<false><<<NNODES / 16, dim3(512), 0, stream>>>(
      ebf, BtE, P, ceid, csrc, rs, b1, S);
  node_update<0><<<NB / 64, dim3(512), 0, stream>>>(S, P, m, h, g,
      BtW2, BtRZ, BtHW, BtP, counts, b2, br, bz, bh);

  edge_fused<true><<<NNODES / 16, dim3(512), 0, stream>>>(
      ebf, BtE, P, ceid, csrc, rs, b1, S);
  node_update<1><<<NB / 64, dim3(512), 0, stream>>>(S, P, m, h, g,
      BtW2, BtRZ, BtHW, BtP, counts, b2, br, bz, bh);

  edge_fused<true><<<NNODES / 16, dim3(512), 0, stream>>>(
      ebf, BtE, P, ceid, csrc, rs, b1, S);
  node_update<2><<<NB / 64, dim3(512), 0, stream>>>(S, P, m, h, g,
      BtW2, BtRZ, BtHW, BtP, counts, b2, br, bz, bh);

  // ------------------------------ readout --------------------------------
  readout2<<<1, blk, 0, stream>>>(g, Wo, bo, (float*)d_out);
}

// Round 9
// 565.082 us; speedup vs baseline: 2.8840x; 2.8840x over previous
//
#include <hip/hip_runtime.h>
#include <hip/hip_bf16.h>

#define E_EDGES 131072
#define NNODES  8192
#define NB      16384   // N_NODES * BATCH rows
#define HID     256
#define EDIM    64
#define MLPH    512
#define OUTD    128
#define NIT     3

typedef short s16x4 __attribute__((ext_vector_type(4)));
typedef short s16x8 __attribute__((ext_vector_type(8)));
typedef float f32x4 __attribute__((ext_vector_type(4)));
typedef float f32x2 __attribute__((ext_vector_type(2)));

__device__ __forceinline__ short f2bf(float f){
  unsigned int x = __builtin_bit_cast(unsigned int, f);
  x += 0x7fffu + ((x >> 16) & 1u);          // RNE
  return (short)(x >> 16);
}
__device__ __forceinline__ float bf2f(short s){
  unsigned int x = ((unsigned int)(unsigned short)s) << 16;
  return __builtin_bit_cast(float, x);
}
__device__ __forceinline__ void gload_lds16(const void* g, void* l){
  __builtin_amdgcn_global_load_lds(
      (const __attribute__((address_space(1))) void*)g,
      (__attribute__((address_space(3))) void*)l, 16, 0, 0);
}
#define MFMA16(a,b,c) __builtin_amdgcn_mfma_f32_16x16x32_bf16((a),(b),(c),0,0,0)

// ---------------- fp8 (e4m3-style) encode/decode ----------------
#if defined(__has_builtin)
#if __has_builtin(__builtin_amdgcn_cvt_pk_f32_fp8) && __has_builtin(__builtin_amdgcn_cvt_pk_fp8_f32)
#define FP8_HW 1
#endif
#endif
#ifndef FP8_HW
#define FP8_HW 0
#endif

__device__ __forceinline__ unsigned char enc_fp8_sw(float f){
  unsigned int b = __builtin_bit_cast(unsigned int, f);
  unsigned int s = (b >> 24) & 0x80u;
  float a = fabsf(f);
  if (a >= 448.f) return (unsigned char)(s | 0x7e);       // clamp to 448
  if (a < 0.015625f){                                      // denorm: m*2^-9
    int q = (int)rintf(a * 512.f);                         // 0..8
    return (unsigned char)(s | (unsigned int)q);           // q==8 -> e=1,m=0
  }
  unsigned int e32  = (b >> 23) & 0xff;
  unsigned int mant = b & 0x7fffff;
  unsigned int rnd  = mant + 0x7ffff + ((mant >> 20) & 1); // RNE at bit 20
  unsigned int e8   = e32 - 120 + (rnd >> 23);
  unsigned int m3   = (rnd >> 20) & 7;
  if (e8 >= 16) return (unsigned char)(s | 0x7e);
  return (unsigned char)(s | (e8 << 3) | m3);
}
__device__ __forceinline__ float dec_fp8_sw(unsigned int v){
  unsigned int s = (v >> 7) & 1, e = (v >> 3) & 15, m = v & 7;
  float r;
  if (e == 0) r = (float)m * 0.001953125f;                 // m * 2^-9
  else        r = __builtin_bit_cast(float, ((e + 120u) << 23) | (m << 20));
  return s ? -r : r;
}
__device__ __forceinline__ unsigned char enc_fp8(float f){
#if FP8_HW
  unsigned int pk = (unsigned int)__builtin_amdgcn_cvt_pk_fp8_f32(f, f, 0, false);
  return (unsigned char)(pk & 0xff);
#else
  return enc_fp8_sw(f);
#endif
}
// decode 4 packed fp8 -> 4 floats
__device__ __forceinline__ void dec_fp8x4(unsigned int ev, float& e0, float& e1,
                                          float& e2, float& e3){
#if FP8_HW
  f32x2 lo = __builtin_amdgcn_cvt_pk_f32_fp8((int)ev, false);
  f32x2 hi = __builtin_amdgcn_cvt_pk_f32_fp8((int)ev, true);
  e0 = lo[0]; e1 = lo[1]; e2 = hi[0]; e3 = hi[1];
#else
  e0 = dec_fp8_sw(ev & 0xff); e1 = dec_fp8_sw((ev >> 8) & 0xff);
  e2 = dec_fp8_sw((ev >> 16) & 0xff); e3 = dec_fp8_sw(ev >> 24);
#endif
}

// ===========================================================================
// e1_gemm — runs ONCE. E1fp8[R][512] = fp8(ef[ceid[R>>1]][R&1] @ A3 + b1),
// R = CSR row (position*2+batch). A gathered f32 + converted in-reg, staged
// to XOR-swizzled LDS; B = pre-swizzled BtE via global_load_lds. 128x128 tile.
// ===========================================================================
__global__ __launch_bounds__(256, 4)
void e1_gemm(const float* __restrict__ ef, const short* __restrict__ BtE,
             unsigned char* __restrict__ E1, const float* __restrict__ b1,
             const int* __restrict__ ceid)
{
  __shared__ __align__(16) short As[128 * 64];
  __shared__ __align__(16) short Bs[128 * 64];

  const int t  = threadIdx.x;
  const int w  = t >> 6, l = t & 63;
  const int lr = l & 15, lg = l >> 4;
  const int wr = w >> 1, wc = w & 1;
  const int browbase = blockIdx.x * 128;
  const int bcolbase = blockIdx.y * 128;
  const int srow = t >> 3;
  const int scol = (t & 7) * 8;            // element offset (8 elems = 16B)

  // ---- stage B (pre-swizzled rows, linear copy) ----
#pragma unroll
  for (int i = 0; i < 4; ++i)
    gload_lds16(BtE + (size_t)(bcolbase + srow + i * 32) * 64 + scol,
                (char*)Bs + w * 1024 + i * 4096);

  // ---- stage A: gather f32, convert, swizzled ds_write ----
#pragma unroll
  for (int i = 0; i < 4; ++i){
    int R = browbase + srow + i * 32;
    int e = ceid[R >> 1];
    const float* ap = ef + ((size_t)e * 2 + (R & 1)) * EDIM + scol;
    f32x4 f0 = *(const f32x4*)ap;
    f32x4 f1 = *(const f32x4*)(ap + 4);
    s16x8 o;
    o[0]=f2bf(f0[0]); o[1]=f2bf(f0[1]); o[2]=f2bf(f0[2]); o[3]=f2bf(f0[3]);
    o[4]=f2bf(f1[0]); o[5]=f2bf(f1[1]); o[6]=f2bf(f1[2]); o[7]=f2bf(f1[3]);
    int row = srow + i * 32;
    *(s16x8*)(As + row * 64 + (scol ^ ((row & 7) << 3))) = o;
  }
  __syncthreads();

  f32x4 acc[4][4];
#pragma unroll
  for (int mm = 0; mm < 4; ++mm)
#pragma unroll
    for (int n = 0; n < 4; ++n) acc[mm][n] = (f32x4){0.f,0.f,0.f,0.f};

#pragma unroll
  for (int kk = 0; kk < 2; ++kk){
    s16x8 a[4], b[4];
#pragma unroll
    for (int mm = 0; mm < 4; ++mm){
      int ar = wr*64 + mm*16 + lr;
      a[mm] = *(const s16x8*)(As + ar * 64 + ((kk*32 + lg*8) ^ ((ar & 7) << 3)));
    }
#pragma unroll
    for (int n = 0; n < 4; ++n){
      int br = wc*64 + n*16 + lr;
      b[n] = *(const s16x8*)(Bs + br * 64 + ((kk*32 + lg*8) ^ ((br & 7) << 3)));
    }
#pragma unroll
    for (int mm = 0; mm < 4; ++mm)
#pragma unroll
      for (int n = 0; n < 4; ++n)
        acc[mm][n] = MFMA16(a[mm], b[n], acc[mm][n]);
  }
#pragma unroll
  for (int mm = 0; mm < 4; ++mm){
    int orow0 = browbase + wr*64 + mm*16 + lg*4;
#pragma unroll
    for (int n = 0; n < 4; ++n){
      int ocol = bcolbase + wc*64 + n*16 + lr;
#pragma unroll
      for (int r = 0; r < 4; ++r)
        E1[(size_t)(orow0 + r) * MLPH + ocol] = enc_fp8(acc[mm][n][r] + b1[ocol]);
    }
  }
}

// ===========================================================================
// edge_kernel: S[n] = sum_{e: dst=n} relu(P1[n] + P2[src] + E1[e])
// E1 is fp8 (4 B per thread per edge, coalesced); P2 s16x4 gather.
// ===========================================================================
template<bool USE_P>
__global__ __launch_bounds__(256)
void edge_kernel(const short* __restrict__ P, const unsigned char* __restrict__ E1,
                 const int* __restrict__ csr_src, const int* __restrict__ row_start,
                 short* __restrict__ S)
{
  const int n = blockIdx.x;
  const int t = threadIdx.x;
  const int b = t >> 7;
  const int j = (t & 127) << 2;
  const int ps = row_start[n], pe = row_start[n + 1];

  float p10 = 0.f, p11 = 0.f, p12 = 0.f, p13 = 0.f;
  if (USE_P){
    s16x4 t1 = *(const s16x4*)(P + (size_t)(n * 2 + b) * 1024 + j);
    p10 = bf2f(t1[0]); p11 = bf2f(t1[1]); p12 = bf2f(t1[2]); p13 = bf2f(t1[3]);
  }
  float a0 = 0.f, a1 = 0.f, a2 = 0.f, a3 = 0.f;
  for (int p = ps; p < pe; ++p){
    unsigned int ev = *(const unsigned int*)(E1 + ((size_t)p * 2 + b) * 512 + j);
    float e0, e1, e2, e3;
    dec_fp8x4(ev, e0, e1, e2, e3);
    float x0 = p10 + e0, x1 = p11 + e1, x2 = p12 + e2, x3 = p13 + e3;
    if (USE_P){
      int src = csr_src[p];
      s16x4 v2 = *(const s16x4*)(P + (size_t)(src * 2 + b) * 1024 + 512 + j);
      x0 += bf2f(v2[0]); x1 += bf2f(v2[1]); x2 += bf2f(v2[2]); x3 += bf2f(v2[3]);
    }
    a0 += fmaxf(x0, 0.f); a1 += fmaxf(x1, 0.f);
    a2 += fmaxf(x2, 0.f); a3 += fmaxf(x3, 0.f);
  }
  s16x4 o; o[0] = f2bf(a0); o[1] = f2bf(a1); o[2] = f2bf(a2); o[3] = f2bf(a3);
  *(s16x4*)(S + (size_t)(n * 2 + b) * 512 + j) = o;
}

// ===========================================================================
// node_update (R7 version, verbatim): block = 64 rows, 512 threads, 256 blks.
// ===========================================================================
template<int PH>
__global__ __launch_bounds__(512, 2)
void node_update(const short* __restrict__ S, short* __restrict__ Pout,
                 float* __restrict__ m, float* __restrict__ h,
                 float* __restrict__ g,
                 const short* __restrict__ BtW2, const short* __restrict__ BtRZ,
                 const short* __restrict__ BtHW, const short* __restrict__ BtP,
                 const int* __restrict__ deg, const float* __restrict__ b2,
                 const float* __restrict__ br, const float* __restrict__ bz,
                 const float* __restrict__ bh)
{
  __shared__ __align__(16) char lds[65536];
  short* Ms = (short*)lds;              // [64][256] bf16 swizzled
  short* Xs = (short*)(lds + 32768);    // [64][256] bf16 swizzled
  float* Hf = (float*)lds;              // [64][256] f32 overlay (PH2 only)

  const int tid = threadIdx.x;
  const int w = tid >> 6, l = tid & 63;
  const int lr = l & 15, lg = l >> 4;
  const int wrow = w >> 2, wcol = w & 3;
  const int rb = wrow * 32;
  const int grow0 = blockIdx.x * 64;

  auto rd256 = [&](int row, int c){ return row * 256 + (c ^ ((row & 7) << 3)); };

  f32x4 hv[2][4], acc[2][4];
#pragma unroll
  for (int i = 0; i < 2; ++i)
#pragma unroll
    for (int j = 0; j < 4; ++j)
#pragma unroll
      for (int r = 0; r < 4; ++r){
        int rl = rb + i*16 + lg*4 + r, colp = wcol*64 + j*16 + lr;
        size_t gi = (size_t)(grow0 + rl) * 256 + colp;
        float base = (float)deg[(grow0 + rl) >> 1] * b2[colp];
        if (PH > 0){ base += m[gi]; hv[i][j][r] = h[gi]; }
        else hv[i][j][r] = 0.f;
        acc[i][j][r] = base;
      }
  if (PH > 0){
#pragma unroll
    for (int i = 0; i < 2; ++i)
#pragma unroll
      for (int j = 0; j < 4; ++j)
#pragma unroll
        for (int r = 0; r < 4; ++r){
          int rl = rb + i*16 + lg*4 + r, colp = wcol*64 + j*16 + lr;
          Xs[rd256(rl, colp)] = f2bf(hv[i][j][r]);
        }
  }

  // ---- Phase A: acc += S @ W2 (K=512) ----
#pragma unroll 4
  for (int c = 0; c < 16; ++c){
    s16x8 a0 = *(const s16x8*)(S + (size_t)(grow0 + rb + lr)      * 512 + c*32 + lg*8);
    s16x8 a1 = *(const s16x8*)(S + (size_t)(grow0 + rb + 16 + lr) * 512 + c*32 + lg*8);
#pragma unroll
    for (int j = 0; j < 4; ++j){
      s16x8 bb = *(const s16x8*)(BtW2 + (size_t)(wcol*64 + j*16 + lr) * 512 + c*32 + lg*8);
      acc[0][j] = MFMA16(a0, bb, acc[0][j]);
      acc[1][j] = MFMA16(a1, bb, acc[1][j]);
    }
  }
#pragma unroll
  for (int i = 0; i < 2; ++i)
#pragma unroll
    for (int j = 0; j < 4; ++j)
#pragma unroll
      for (int r = 0; r < 4; ++r){
        int rl = rb + i*16 + lg*4 + r, colp = wcol*64 + j*16 + lr;
        float v = acc[i][j][r];
        if (PH < 2) m[(size_t)(grow0 + rl) * 256 + colp] = v;
        Ms[rd256(rl, colp)] = f2bf(v);
      }
  __syncthreads();

  // ---- Phase B+C: Gr, Gz ----
  f32x4 Gr[2][4], Gz[2][4];
#pragma unroll
  for (int i = 0; i < 2; ++i)
#pragma unroll
    for (int j = 0; j < 4; ++j){ Gr[i][j] = (f32x4){0.f,0.f,0.f,0.f}; Gz[i][j] = (f32x4){0.f,0.f,0.f,0.f}; }

  auto gemmRZ = [&](const short* Ab, int koff){
#pragma unroll 2
    for (int c = 0; c < 8; ++c){
      s16x8 a0 = *(const s16x8*)(Ab + rd256(rb + lr,      c*32 + lg*8));
      s16x8 a1 = *(const s16x8*)(Ab + rd256(rb + 16 + lr, c*32 + lg*8));
#pragma unroll
      for (int j = 0; j < 4; ++j){
        int colr = wcol*64 + j*16 + lr;
        s16x8 b_r = *(const s16x8*)(BtRZ + (size_t)colr         * 512 + koff + c*32 + lg*8);
        s16x8 b_z = *(const s16x8*)(BtRZ + (size_t)(256 + colr) * 512 + koff + c*32 + lg*8);
        Gr[0][j] = MFMA16(a0, b_r, Gr[0][j]);
        Gr[1][j] = MFMA16(a1, b_r, Gr[1][j]);
        Gz[0][j] = MFMA16(a0, b_z, Gz[0][j]);
        Gz[1][j] = MFMA16(a1, b_z, Gz[1][j]);
      }
    }
  };
  gemmRZ(Ms, 0);
  if (PH > 0) gemmRZ(Xs, 256);

  // ---- e1: r, z; Xs <- bf16(r*h) ----
  f32x4 zz[2][4];
#pragma unroll
  for (int i = 0; i < 2; ++i)
#pragma unroll
    for (int j = 0; j < 4; ++j)
#pragma unroll
      for (int r = 0; r < 4; ++r){
        int colp = wcol*64 + j*16 + lr;
        zz[i][j][r] = 1.f / (1.f + __expf(-(Gz[i][j][r] + bz[colp])));
      }
  if (PH > 0){
    __syncthreads();
#pragma unroll
    for (int i = 0; i < 2; ++i)
#pragma unroll
      for (int j = 0; j < 4; ++j)
#pragma unroll
        for (int r = 0; r < 4; ++r){
          int rl = rb + i*16 + lg*4 + r, colp = wcol*64 + j*16 + lr;
          float rr = 1.f / (1.f + __expf(-(Gr[i][j][r] + br[colp])));
          Xs[rd256(rl, colp)] = f2bf(rr * hv[i][j][r]);
        }
    __syncthreads();
  }

  // ---- Phase D: Gw ----
  f32x4 Gw[2][4];
#pragma unroll
  for (int i = 0; i < 2; ++i)
#pragma unroll
    for (int j = 0; j < 4; ++j) Gw[i][j] = (f32x4){0.f,0.f,0.f,0.f};
  auto gemmHW = [&](const short* Ab, int koff){
#pragma unroll 2
    for (int c = 0; c < 8; ++c){
      s16x8 a0 = *(const s16x8*)(Ab + rd256(rb + lr,      c*32 + lg*8));
      s16x8 a1 = *(const s16x8*)(Ab + rd256(rb + 16 + lr, c*32 + lg*8));
#pragma unroll
      for (int j = 0; j < 4; ++j){
        s16x8 bb = *(const s16x8*)(BtHW + (size_t)(wcol*64 + j*16 + lr) * 512 + koff + c*32 + lg*8);
        Gw[0][j] = MFMA16(a0, bb, Gw[0][j]);
        Gw[1][j] = MFMA16(a1, bb, Gw[1][j]);
      }
    }
  };
  gemmHW(Ms, 0);
  if (PH > 0) gemmHW(Xs, 256);
  __syncthreads();

  // ---- e2: h' ----
#pragma unroll
  for (int i = 0; i < 2; ++i)
#pragma unroll
    for (int j = 0; j < 4; ++j)
#pragma unroll
      for (int r = 0; r < 4; ++r){
        int rl = rb + i*16 + lg*4 + r, colp = wcol*64 + j*16 + lr;
        float ht = tanhf(Gw[i][j][r] + bh[colp]);
        float z  = zz[i][j][r];
        float hn = (1.f - z) * hv[i][j][r] + z * ht;
        if (PH < 2){
          h[(size_t)(grow0 + rl) * 256 + colp] = hn;
          Ms[rd256(rl, colp)] = f2bf(hn);
        } else {
          Hf[rl * 256 + colp] = hn;
        }
      }
  __syncthreads();

  if (PH < 2){
    for (int pn = 0; pn < 4; ++pn){
      f32x4 pa0[4], pa1[4];
#pragma unroll
      for (int j = 0; j < 4; ++j){ pa0[j] = (f32x4){0.f,0.f,0.f,0.f}; pa1[j] = (f32x4){0.f,0.f,0.f,0.f}; }
#pragma unroll 2
      for (int c = 0; c < 8; ++c){
        s16x8 a0 = *(const s16x8*)(Ms + rd256(rb + lr,      c*32 + lg*8));
        s16x8 a1 = *(const s16x8*)(Ms + rd256(rb + 16 + lr, c*32 + lg*8));
#pragma unroll
        for (int j = 0; j < 4; ++j){
          s16x8 bb = *(const s16x8*)(BtP + (size_t)(pn*256 + wcol*64 + j*16 + lr) * 256 + c*32 + lg*8);
          pa0[j] = MFMA16(a0, bb, pa0[j]);
          pa1[j] = MFMA16(a1, bb, pa1[j]);
        }
      }
#pragma unroll
      for (int j = 0; j < 4; ++j)
#pragma unroll
        for (int r = 0; r < 4; ++r){
          int colp = wcol*64 + j*16 + lr;
          Pout[(size_t)(grow0 + rb + lg*4 + r)      * 1024 + pn*256 + colp] = f2bf(pa0[j][r]);
          Pout[(size_t)(grow0 + rb + 16 + lg*4 + r) * 1024 + pn*256 + colp] = f2bf(pa1[j][r]);
        }
    }
  } else {
    int col = tid & 255, pb = tid >> 8;
    float s = 0.f;
#pragma unroll
    for (int rr = 0; rr < 32; ++rr)
      s += Hf[(2*rr + pb) * 256 + col];
    atomicAdd(&g[pb * 256 + col], s);
  }
}

// ------------------------------- CSR build ---------------------------------
__global__ void count_kernel(const int* __restrict__ edst, int* __restrict__ counts){
  int e = blockIdx.x * 256 + threadIdx.x;
  if (e < E_EDGES) atomicAdd(&counts[edst[e]], 1);
}
__global__ void scan_kernel(const int* __restrict__ counts, int* __restrict__ row_start,
                            int* __restrict__ cursor){
  __shared__ int sums[1024];
  int t = threadIdx.x;
  int base = t * 8;
  int loc[8]; int s = 0;
#pragma unroll
  for (int i = 0; i < 8; ++i){ loc[i] = s; s += counts[base + i]; }
  sums[t] = s;
  __syncthreads();
  for (int o = 1; o < 1024; o <<= 1){
    int v = sums[t];
    int u = (t >= o) ? sums[t - o] : 0;
    __syncthreads();
    sums[t] = v + u;
    __syncthreads();
  }
  int excl = (t == 0) ? 0 : sums[t - 1];
#pragma unroll
  for (int i = 0; i < 8; ++i){ int v = excl + loc[i]; row_start[base + i] = v; cursor[base + i] = v; }
  if (t == 1023) row_start[NNODES] = sums[1023];
}
__global__ void fill_kernel(const int* __restrict__ edst, const int* __restrict__ esrc,
                            int* __restrict__ cursor, int* __restrict__ csr_eid,
                            int* __restrict__ csr_src){
  int e = blockIdx.x * 256 + threadIdx.x;
  if (e < E_EDGES){
    int pos = atomicAdd(&cursor[edst[e]], 1);
    csr_eid[pos] = e;
    csr_src[pos] = esrc[e];
  }
}

// --------------------------- weight repacking ------------------------------
// BtP [1024][256], BtE [512][64] PRE-SWIZZLED (8-elem unit ^= row&7),
// BtW2 [256][512], BtRZ [512][512], BtHW [256][512]
__global__ void prep_weights(const float* __restrict__ W1, const float* __restrict__ W2,
                             const float* __restrict__ Wr, const float* __restrict__ Ur,
                             const float* __restrict__ Wz, const float* __restrict__ Uz,
                             const float* __restrict__ Wh, const float* __restrict__ Uh,
                             short* __restrict__ BtP, short* __restrict__ BtE,
                             short* __restrict__ BtW2, short* __restrict__ BtRZ,
                             short* __restrict__ BtHW)
{
  int id = blockIdx.x * 256 + threadIdx.x;
  if (id < 262144){                       // BtP
    int jj = id >> 8, k = id & 255;
    float v = (jj < 512) ? W1[(size_t)k * 512 + jj] : W1[(size_t)(256 + k) * 512 + (jj - 512)];
    BtP[id] = f2bf(v);
  } else if (id < 294912){                // BtE pre-swizzled
    int i2 = id - 262144; int jj = i2 >> 6, c = i2 & 63;
    BtE[jj * 64 + (c ^ ((jj & 7) << 3))] = f2bf(W1[(size_t)(512 + c) * 512 + jj]);
  } else if (id < 425984){                // BtW2
    int i2 = id - 294912; int n = i2 >> 9, k = i2 & 511;
    BtW2[i2] = f2bf(W2[(size_t)k * 256 + n]);
  } else if (id < 688128){                // BtRZ
    int i2 = id - 425984; int col = i2 >> 9, k = i2 & 511;
    float v;
    if (col < 256) v = (k < 256) ? Wr[(size_t)k * 256 + col] : Ur[(size_t)(k - 256) * 256 + col];
    else { int c2 = col - 256; v = (k < 256) ? Wz[(size_t)k * 256 + c2] : Uz[(size_t)(k - 256) * 256 + c2]; }
    BtRZ[i2] = f2bf(v);
  } else if (id < 819200){                // BtHW
    int i2 = id - 688128; int col = i2 >> 9, k = i2 & 511;
    float v = (k < 256) ? Wh[(size_t)k * 256 + col] : Uh[(size_t)(k - 256) * 256 + col];
    BtHW[i2] = f2bf(v);
  }
}

// -------------------------------- readout ----------------------------------
__global__ __launch_bounds__(256)
void readout2(const float* __restrict__ g, const float* __restrict__ Wo,
              const float* __restrict__ bo, float* __restrict__ out){
  int t = threadIdx.x;
  int b = t >> 7, o = t & 127;
  float s = bo[o];
  for (int c = 0; c < 256; ++c) s += g[b * 256 + c] * Wo[c * 128 + o];
  out[b * 128 + o] = s;
}

// ===========================================================================
extern "C" void kernel_launch(void* const* d_in, const int* in_sizes, int n_in,
                              void* d_out, int out_size, void* d_ws, size_t ws_size,
                              hipStream_t stream)
{
  const float* ef  = (const float*)d_in[0];
  const float* W1  = (const float*)d_in[1];
  const float* b1  = (const float*)d_in[2];
  const float* W2  = (const float*)d_in[3];
  const float* b2  = (const float*)d_in[4];
  const float* Wr  = (const float*)d_in[5];
  const float* Ur  = (const float*)d_in[6];
  const float* br  = (const float*)d_in[7];
  const float* Wz  = (const float*)d_in[8];
  const float* Uz  = (const float*)d_in[9];
  const float* bz  = (const float*)d_in[10];
  const float* Wh  = (const float*)d_in[11];
  const float* Uh  = (const float*)d_in[12];
  const float* bh  = (const float*)d_in[13];
  const float* Wo  = (const float*)d_in[14];
  const float* bo  = (const float*)d_in[15];
  const int* esrc  = (const int*)d_in[16];
  const int* edst  = (const int*)d_in[17];

  char* base = (char*)d_ws;
  size_t off = 0;
  auto alloc = [&](size_t bytes) -> char* {
    off = (off + 255) & ~(size_t)255;
    char* p = base + off;
    off += bytes;
    return p;
  };
  float* h    = (float*)alloc((size_t)NB * 256 * 4);            // 16 MB
  float* m    = (float*)alloc((size_t)NB * 256 * 4);            // 16 MB
  short* P    = (short*)alloc((size_t)NB * 1024 * 2);           // 32 MB
  short* S    = (short*)alloc((size_t)NB * 512 * 2);            // 16 MB
  unsigned char* E1 = (unsigned char*)alloc((size_t)E_EDGES * 2 * MLPH); // 128 MiB
  short* BtP  = (short*)alloc(262144 * 2);
  short* BtE  = (short*)alloc(32768 * 2);
  short* BtW2 = (short*)alloc(131072 * 2);
  short* BtRZ = (short*)alloc(262144 * 2);
  short* BtHW = (short*)alloc(131072 * 2);
  int* counts = (int*)alloc(NNODES * 4);
  int* rs     = (int*)alloc((NNODES + 1) * 4);
  int* cursor = (int*)alloc(NNODES * 4);
  int* ceid   = (int*)alloc(E_EDGES * 4);
  int* csrc   = (int*)alloc(E_EDGES * 4);
  float* g    = (float*)alloc(512 * 4);
  // total ~216 MB < 256 MiB workspace

  dim3 blk(256);

  // ------------------------------- prep ----------------------------------
  hipMemsetAsync(g,  0, 512 * 4, stream);
  hipMemsetAsync(counts, 0, NNODES * 4, stream);
  prep_weights<<<3200, blk, 0, stream>>>(W1, W2, Wr, Ur, Wz, Uz, Wh, Uh,
                                         BtP, BtE, BtW2, BtRZ, BtHW);
  count_kernel<<<512, blk, 0, stream>>>(edst, counts);
  scan_kernel<<<1, 1024, 0, stream>>>(counts, rs, cursor);
  fill_kernel<<<512, blk, 0, stream>>>(edst, esrc, cursor, ceid, csrc);

  // E1 (fp8) computed ONCE — iteration-invariant
  e1_gemm<<<dim3(E_EDGES * 2 / 128, MLPH / 128), blk, 0, stream>>>(
      ef, BtE, E1, b1, ceid);

  // ----------------------------- iterations ------------------------------
  edge_kernel<false><<<NNODES, blk, 0, stream>>>(P, E1, csrc, rs, S);
  node_update<0><<<NB / 64, dim3(512), 0, stream>>>(S, P, m, h, g,
      BtW2, BtRZ, BtHW, BtP, counts, b2, br, bz, bh);

  edge_kernel<true><<<NNODES, blk, 0, stream>>>(P, E1, csrc, rs, S);
  node_update<1><<<NB / 64, dim3(512), 0, stream>>>(S, P, m, h, g,
      BtW2, BtRZ, BtHW, BtP, counts, b2, br, bz, bh);

  edge_kernel<true><<<NNODES, blk, 0, stream>>>(P, E1, csrc, rs, S);
  node_update<2><<<NB / 64, dim3(512), 0, stream>>>(S, P, m, h, g,
      BtW2, BtRZ, BtHW, BtP, counts, b2, br, bz, bh);

  // ------------------------------ readout --------------------------------
  readout2<<<1, blk, 0, stream>>>(g, Wo, bo, (float*)d_out);
}

// Round 10
// 455.406 us; speedup vs baseline: 3.5786x; 1.2408x over previous
//
#include <hip/hip_runtime.h>
#include <hip/hip_bf16.h>

#define E_EDGES 131072
#define NNODES  8192
#define NB      16384   // N_NODES * BATCH rows
#define HID     256
#define EDIM    64
#define MLPH    512
#define OUTD    128
#define NIT     3
#define RB      32      // rows per node_update block

typedef short s16x4 __attribute__((ext_vector_type(4)));
typedef short s16x8 __attribute__((ext_vector_type(8)));
typedef float f32x4 __attribute__((ext_vector_type(4)));
typedef float f32x2 __attribute__((ext_vector_type(2)));

__device__ __forceinline__ short f2bf(float f){
  unsigned int x = __builtin_bit_cast(unsigned int, f);
  x += 0x7fffu + ((x >> 16) & 1u);          // RNE
  return (short)(x >> 16);
}
__device__ __forceinline__ float bf2f(short s){
  unsigned int x = ((unsigned int)(unsigned short)s) << 16;
  return __builtin_bit_cast(float, x);
}
__device__ __forceinline__ void gload_lds16(const void* g, void* l){
  __builtin_amdgcn_global_load_lds(
      (const __attribute__((address_space(1))) void*)g,
      (__attribute__((address_space(3))) void*)l, 16, 0, 0);
}
#define MFMA16(a,b,c) __builtin_amdgcn_mfma_f32_16x16x32_bf16((a),(b),(c),0,0,0)

// ---------------- fp8 (e4m3-style) encode/decode ----------------
#if defined(__has_builtin)
#if __has_builtin(__builtin_amdgcn_cvt_pk_f32_fp8) && __has_builtin(__builtin_amdgcn_cvt_pk_fp8_f32)
#define FP8_HW 1
#endif
#endif
#ifndef FP8_HW
#define FP8_HW 0
#endif

__device__ __forceinline__ unsigned char enc_fp8_sw(float f){
  unsigned int b = __builtin_bit_cast(unsigned int, f);
  unsigned int s = (b >> 24) & 0x80u;
  float a = fabsf(f);
  if (a >= 448.f) return (unsigned char)(s | 0x7e);       // clamp to 448
  if (a < 0.015625f){                                      // denorm: m*2^-9
    int q = (int)rintf(a * 512.f);                         // 0..8
    return (unsigned char)(s | (unsigned int)q);           // q==8 -> e=1,m=0
  }
  unsigned int e32  = (b >> 23) & 0xff;
  unsigned int mant = b & 0x7fffff;
  unsigned int rnd  = mant + 0x7ffff + ((mant >> 20) & 1); // RNE at bit 20
  unsigned int e8   = e32 - 120 + (rnd >> 23);
  unsigned int m3   = (rnd >> 20) & 7;
  if (e8 >= 16) return (unsigned char)(s | 0x7e);
  return (unsigned char)(s | (e8 << 3) | m3);
}
__device__ __forceinline__ float dec_fp8_sw(unsigned int v){
  unsigned int s = (v >> 7) & 1, e = (v >> 3) & 15, m = v & 7;
  float r;
  if (e == 0) r = (float)m * 0.001953125f;                 // m * 2^-9
  else        r = __builtin_bit_cast(float, ((e + 120u) << 23) | (m << 20));
  return s ? -r : r;
}
__device__ __forceinline__ unsigned char enc_fp8(float f){
#if FP8_HW
  unsigned int pk = (unsigned int)__builtin_amdgcn_cvt_pk_fp8_f32(f, f, 0, false);
  return (unsigned char)(pk & 0xff);
#else
  return enc_fp8_sw(f);
#endif
}
__device__ __forceinline__ void dec_fp8x4(unsigned int ev, float& e0, float& e1,
                                          float& e2, float& e3){
#if FP8_HW
  f32x2 lo = __builtin_amdgcn_cvt_pk_f32_fp8((int)ev, false);
  f32x2 hi = __builtin_amdgcn_cvt_pk_f32_fp8((int)ev, true);
  e0 = lo[0]; e1 = lo[1]; e2 = hi[0]; e3 = hi[1];
#else
  e0 = dec_fp8_sw(ev & 0xff); e1 = dec_fp8_sw((ev >> 8) & 0xff);
  e2 = dec_fp8_sw((ev >> 16) & 0xff); e3 = dec_fp8_sw(ev >> 24);
#endif
}

// ===========================================================================
// e1_gemm — runs ONCE. E1fp8[R][512] = fp8(ef[ceid[R>>1]][R&1] @ A3 + b1).
// ===========================================================================
__global__ __launch_bounds__(256, 4)
void e1_gemm(const float* __restrict__ ef, const short* __restrict__ BtE,
             unsigned char* __restrict__ E1, const float* __restrict__ b1,
             const int* __restrict__ ceid)
{
  __shared__ __align__(16) short As[128 * 64];
  __shared__ __align__(16) short Bs[128 * 64];

  const int t  = threadIdx.x;
  const int w  = t >> 6, l = t & 63;
  const int lr = l & 15, lg = l >> 4;
  const int wr = w >> 1, wc = w & 1;
  const int browbase = blockIdx.x * 128;
  const int bcolbase = blockIdx.y * 128;
  const int srow = t >> 3;
  const int scol = (t & 7) * 8;

#pragma unroll
  for (int i = 0; i < 4; ++i)
    gload_lds16(BtE + (size_t)(bcolbase + srow + i * 32) * 64 + scol,
                (char*)Bs + w * 1024 + i * 4096);

#pragma unroll
  for (int i = 0; i < 4; ++i){
    int R = browbase + srow + i * 32;
    int e = ceid[R >> 1];
    const float* ap = ef + ((size_t)e * 2 + (R & 1)) * EDIM + scol;
    f32x4 f0 = *(const f32x4*)ap;
    f32x4 f1 = *(const f32x4*)(ap + 4);
    s16x8 o;
    o[0]=f2bf(f0[0]); o[1]=f2bf(f0[1]); o[2]=f2bf(f0[2]); o[3]=f2bf(f0[3]);
    o[4]=f2bf(f1[0]); o[5]=f2bf(f1[1]); o[6]=f2bf(f1[2]); o[7]=f2bf(f1[3]);
    int row = srow + i * 32;
    *(s16x8*)(As + row * 64 + (scol ^ ((row & 7) << 3))) = o;
  }
  __syncthreads();

  f32x4 acc[4][4];
#pragma unroll
  for (int mm = 0; mm < 4; ++mm)
#pragma unroll
    for (int n = 0; n < 4; ++n) acc[mm][n] = (f32x4){0.f,0.f,0.f,0.f};

#pragma unroll
  for (int kk = 0; kk < 2; ++kk){
    s16x8 a[4], b[4];
#pragma unroll
    for (int mm = 0; mm < 4; ++mm){
      int ar = wr*64 + mm*16 + lr;
      a[mm] = *(const s16x8*)(As + ar * 64 + ((kk*32 + lg*8) ^ ((ar & 7) << 3)));
    }
#pragma unroll
    for (int n = 0; n < 4; ++n){
      int br = wc*64 + n*16 + lr;
      b[n] = *(const s16x8*)(Bs + br * 64 + ((kk*32 + lg*8) ^ ((br & 7) << 3)));
    }
#pragma unroll
    for (int mm = 0; mm < 4; ++mm)
#pragma unroll
      for (int n = 0; n < 4; ++n)
        acc[mm][n] = MFMA16(a[mm], b[n], acc[mm][n]);
  }
#pragma unroll
  for (int mm = 0; mm < 4; ++mm){
    int orow0 = browbase + wr*64 + mm*16 + lg*4;
#pragma unroll
    for (int n = 0; n < 4; ++n){
      int ocol = bcolbase + wc*64 + n*16 + lr;
#pragma unroll
      for (int r = 0; r < 4; ++r)
        E1[(size_t)(orow0 + r) * MLPH + ocol] = enc_fp8(acc[mm][n][r] + b1[ocol]);
    }
  }
}

// ===========================================================================
// edge_kernel: S[n] = sum_{e: dst=n} relu(P1[n] + P2[src] + E1[e])  (E1 fp8)
// ===========================================================================
template<bool USE_P>
__global__ __launch_bounds__(256)
void edge_kernel(const short* __restrict__ P, const unsigned char* __restrict__ E1,
                 const int* __restrict__ csr_src, const int* __restrict__ row_start,
                 short* __restrict__ S)
{
  const int n = blockIdx.x;
  const int t = threadIdx.x;
  const int b = t >> 7;
  const int j = (t & 127) << 2;
  const int ps = row_start[n], pe = row_start[n + 1];

  float p10 = 0.f, p11 = 0.f, p12 = 0.f, p13 = 0.f;
  if (USE_P){
    s16x4 t1 = *(const s16x4*)(P + (size_t)(n * 2 + b) * 1024 + j);
    p10 = bf2f(t1[0]); p11 = bf2f(t1[1]); p12 = bf2f(t1[2]); p13 = bf2f(t1[3]);
  }
  float a0 = 0.f, a1 = 0.f, a2 = 0.f, a3 = 0.f;
  for (int p = ps; p < pe; ++p){
    unsigned int ev = *(const unsigned int*)(E1 + ((size_t)p * 2 + b) * 512 + j);
    float e0, e1, e2, e3;
    dec_fp8x4(ev, e0, e1, e2, e3);
    float x0 = p10 + e0, x1 = p11 + e1, x2 = p12 + e2, x3 = p13 + e3;
    if (USE_P){
      int src = csr_src[p];
      s16x4 v2 = *(const s16x4*)(P + (size_t)(src * 2 + b) * 1024 + 512 + j);
      x0 += bf2f(v2[0]); x1 += bf2f(v2[1]); x2 += bf2f(v2[2]); x3 += bf2f(v2[3]);
    }
    a0 += fmaxf(x0, 0.f); a1 += fmaxf(x1, 0.f);
    a2 += fmaxf(x2, 0.f); a3 += fmaxf(x3, 0.f);
  }
  s16x4 o; o[0] = f2bf(a0); o[1] = f2bf(a1); o[2] = f2bf(a2); o[3] = f2bf(a3);
  *(s16x4*)(S + (size_t)(n * 2 + b) * 512 + j) = o;
}

// ===========================================================================
// node_update v3 — R3-proven staged-B structure + PH specialization.
// Block = 32 rows (16 nodes), 256 thr (4 col-waves), 512 blocks (2/CU).
// LDS: As[32][64] 4KB + Bs[256][64] 32KB + Ms 16KB + Xs 16KB = 68KB.
// All LDS tiles XOR-16B swizzled; staging via pre-swizzled global source.
// PH0: h=0,m=0 -> B/C/D only K=0..255 (4 chunks), no m/h reads, no rh pass.
// PH2: no m/h/P writes; in-LDS readout.
// ===========================================================================
template<int PH>
__global__ __launch_bounds__(256, 2)
void node_update(const short* __restrict__ S, short* __restrict__ Pout,
                 float* __restrict__ m, float* __restrict__ h,
                 float* __restrict__ g,
                 const short* __restrict__ BtW2, const short* __restrict__ BtRZ,
                 const short* __restrict__ BtHW, const short* __restrict__ BtP,
                 const int* __restrict__ deg, const float* __restrict__ b2,
                 const float* __restrict__ br, const float* __restrict__ bz,
                 const float* __restrict__ bh)
{
  __shared__ __align__(16) char lds[69632];
  short* As = (short*)lds;             // [32][64]   4KB
  short* Bs = (short*)(lds + 4096);    // [256][64] 32KB
  short* Ms = (short*)(lds + 36864);   // [32][256] 16KB
  short* Xs = (short*)(lds + 53248);   // [32][256] 16KB
  float* Hf = (float*)lds;             // [32][256] 32KB overlay (PH2 only)

  const int tid = threadIdx.x;
  const int w = tid >> 6, l = tid & 63;
  const int lr = l & 15, lg = l >> 4;
  const int grow0 = blockIdx.x * RB;

  auto stageB = [&](const short* Bt, int K, int pcol0, int k0){
#pragma unroll
    for (int i = 0; i < 8; ++i){
      int u = i * 256 + tid;
      int row = u >> 3, uc = u & 7;
      const short* gp = Bt + (size_t)(pcol0 + row) * K + k0 + ((uc ^ (row & 7)) << 3);
      gload_lds16(gp, (char*)Bs + i * 4096 + w * 1024);
    }
  };
  auto stageA_S = [&](int k0){
    int row = tid >> 3, uc = tid & 7;
    const short* gp = S + (size_t)(grow0 + row) * 512 + k0 + ((uc ^ (row & 7)) << 3);
    gload_lds16(gp, (char*)As + w * 1024);
  };
  auto rdA64 = [&](int row, int colel){ return row * 64 + (colel ^ ((row & 7) << 3)); };
  auto rd256 = [&](int row, int colel){ return row * 256 + (colel ^ ((row & 7) << 3)); };

  // ---- h into regs, acc init = m + deg*b2; Xs <- bf16(h) ----
  f32x4 hv[2][4], acc[2][4];
#pragma unroll
  for (int i = 0; i < 2; ++i)
#pragma unroll
    for (int j = 0; j < 4; ++j)
#pragma unroll
      for (int r = 0; r < 4; ++r){
        int rl = i*16 + lg*4 + r, colp = w*64 + j*16 + lr;
        size_t gi = (size_t)(grow0 + rl) * 256 + colp;
        float base = (float)deg[(grow0 + rl) >> 1] * b2[colp];
        if (PH > 0){ base += m[gi]; hv[i][j][r] = h[gi]; }
        else hv[i][j][r] = 0.f;
        acc[i][j][r] = base;
      }
  if (PH > 0){
#pragma unroll
    for (int i = 0; i < 2; ++i)
#pragma unroll
      for (int j = 0; j < 4; ++j)
#pragma unroll
        for (int r = 0; r < 4; ++r){
          int rl = i*16 + lg*4 + r, colp = w*64 + j*16 + lr;
          Xs[rd256(rl, colp)] = f2bf(hv[i][j][r]);
        }
  }

  // ---- Phase A: acc += S @ W2 (K=512, 8 staged chunks) ----
  for (int c = 0; c < 8; ++c){
    __syncthreads();
    stageA_S(c * 64);
    stageB(BtW2, 512, 0, c * 64);
    __syncthreads();
#pragma unroll
    for (int kk = 0; kk < 2; ++kk){
      s16x8 a0 = *(const s16x8*)(As + rdA64(lr,      kk*32 + lg*8));
      s16x8 a1 = *(const s16x8*)(As + rdA64(16 + lr, kk*32 + lg*8));
#pragma unroll
      for (int j = 0; j < 4; ++j){
        s16x8 bb = *(const s16x8*)(Bs + rdA64(w*64 + j*16 + lr, kk*32 + lg*8));
        acc[0][j] = MFMA16(a0, bb, acc[0][j]);
        acc[1][j] = MFMA16(a1, bb, acc[1][j]);
      }
    }
  }
#pragma unroll
  for (int i = 0; i < 2; ++i)
#pragma unroll
    for (int j = 0; j < 4; ++j)
#pragma unroll
      for (int r = 0; r < 4; ++r){
        int rl = i*16 + lg*4 + r, colp = w*64 + j*16 + lr;
        float v = acc[i][j][r];
        if (PH < 2) m[(size_t)(grow0 + rl) * 256 + colp] = v;
        Ms[rd256(rl, colp)] = f2bf(v);
      }

  const int NC = (PH > 0) ? 8 : 4;       // gate K-chunks (PH0: U-half is zero)

  // ---- Phase B: Gr ----
  f32x4 Gr[2][4], Gz[2][4];
#pragma unroll
  for (int i = 0; i < 2; ++i)
#pragma unroll
    for (int j = 0; j < 4; ++j){ Gr[i][j] = (f32x4){0.f,0.f,0.f,0.f}; Gz[i][j] = (f32x4){0.f,0.f,0.f,0.f}; }

  for (int c = 0; c < NC; ++c){
    __syncthreads();
    stageB(BtRZ, 512, 0, c * 64);
    __syncthreads();
    const short* Ab = (c < 4) ? Ms : Xs;
    int kb = (c & 3) * 64;
#pragma unroll
    for (int kk = 0; kk < 2; ++kk){
      s16x8 a0 = *(const s16x8*)(Ab + rd256(lr,      kb + kk*32 + lg*8));
      s16x8 a1 = *(const s16x8*)(Ab + rd256(16 + lr, kb + kk*32 + lg*8));
#pragma unroll
      for (int j = 0; j < 4; ++j){
        s16x8 bb = *(const s16x8*)(Bs + rdA64(w*64 + j*16 + lr, kk*32 + lg*8));
        Gr[0][j] = MFMA16(a0, bb, Gr[0][j]);
        Gr[1][j] = MFMA16(a1, bb, Gr[1][j]);
      }
    }
  }
  // ---- Phase C: Gz ----
  for (int c = 0; c < NC; ++c){
    __syncthreads();
    stageB(BtRZ, 512, 256, c * 64);
    __syncthreads();
    const short* Ab = (c < 4) ? Ms : Xs;
    int kb = (c & 3) * 64;
#pragma unroll
    for (int kk = 0; kk < 2; ++kk){
      s16x8 a0 = *(const s16x8*)(Ab + rd256(lr,      kb + kk*32 + lg*8));
      s16x8 a1 = *(const s16x8*)(Ab + rd256(16 + lr, kb + kk*32 + lg*8));
#pragma unroll
      for (int j = 0; j < 4; ++j){
        s16x8 bb = *(const s16x8*)(Bs + rdA64(w*64 + j*16 + lr, kk*32 + lg*8));
        Gz[0][j] = MFMA16(a0, bb, Gz[0][j]);
        Gz[1][j] = MFMA16(a1, bb, Gz[1][j]);
      }
    }
  }

  // ---- e1: r, z; Xs <- bf16(r*h) ----
  f32x4 zz[2][4];
#pragma unroll
  for (int i = 0; i < 2; ++i)
#pragma unroll
    for (int j = 0; j < 4; ++j)
#pragma unroll
      for (int r = 0; r < 4; ++r){
        int colp = w*64 + j*16 + lr;
        zz[i][j][r] = 1.f / (1.f + __expf(-(Gz[i][j][r] + bz[colp])));
      }
  if (PH > 0){
    __syncthreads();                     // B/C's Xs(hb) reads done
#pragma unroll
    for (int i = 0; i < 2; ++i)
#pragma unroll
      for (int j = 0; j < 4; ++j)
#pragma unroll
        for (int r = 0; r < 4; ++r){
          int rl = i*16 + lg*4 + r, colp = w*64 + j*16 + lr;
          float rr = 1.f / (1.f + __expf(-(Gr[i][j][r] + br[colp])));
          Xs[rd256(rl, colp)] = f2bf(rr * hv[i][j][r]);
        }
    __syncthreads();                     // Xs(rh) visible
  }

  // ---- Phase D: Gw = [m|rh] @ BtHW ----
  f32x4 Gw[2][4];
#pragma unroll
  for (int i = 0; i < 2; ++i)
#pragma unroll
    for (int j = 0; j < 4; ++j) Gw[i][j] = (f32x4){0.f,0.f,0.f,0.f};
  for (int c = 0; c < NC; ++c){
    __syncthreads();
    stageB(BtHW, 512, 0, c * 64);
    __syncthreads();
    const short* Ab = (c < 4) ? Ms : Xs;
    int kb = (c & 3) * 64;
#pragma unroll
    for (int kk = 0; kk < 2; ++kk){
      s16x8 a0 = *(const s16x8*)(Ab + rd256(lr,      kb + kk*32 + lg*8));
      s16x8 a1 = *(const s16x8*)(Ab + rd256(16 + lr, kb + kk*32 + lg*8));
#pragma unroll
      for (int j = 0; j < 4; ++j){
        s16x8 bb = *(const s16x8*)(Bs + rdA64(w*64 + j*16 + lr, kk*32 + lg*8));
        Gw[0][j] = MFMA16(a0, bb, Gw[0][j]);
        Gw[1][j] = MFMA16(a1, bb, Gw[1][j]);
      }
    }
  }

  // ---- e2: h' ----
  __syncthreads();                       // D's Ms/Xs reads done
#pragma unroll
  for (int i = 0; i < 2; ++i)
#pragma unroll
    for (int j = 0; j < 4; ++j)
#pragma unroll
      for (int r = 0; r < 4; ++r){
        int rl = i*16 + lg*4 + r, colp = w*64 + j*16 + lr;
        float ht = tanhf(Gw[i][j][r] + bh[colp]);
        float z  = zz[i][j][r];
        float hn = (1.f - z) * hv[i][j][r] + z * ht;
        if (PH < 2){
          h[(size_t)(grow0 + rl) * 256 + colp] = hn;
          Ms[rd256(rl, colp)] = f2bf(hn);
        } else {
          Hf[rl * 256 + colp] = hn;
        }
      }
  __syncthreads();                       // Ms(h') / Hf visible

  if (PH < 2){
    // ---- Phase E: P = h' @ BtP, 4 panels of 256 cols ----
    for (int pn = 0; pn < 4; ++pn){
      f32x4 pa0[4], pa1[4];
#pragma unroll
      for (int j = 0; j < 4; ++j){ pa0[j] = (f32x4){0.f,0.f,0.f,0.f}; pa1[j] = (f32x4){0.f,0.f,0.f,0.f}; }
      for (int c = 0; c < 4; ++c){
        __syncthreads();
        stageB(BtP, 256, pn * 256, c * 64);
        __syncthreads();
#pragma unroll
        for (int kk = 0; kk < 2; ++kk){
          s16x8 a0 = *(const s16x8*)(Ms + rd256(lr,      c*64 + kk*32 + lg*8));
          s16x8 a1 = *(const s16x8*)(Ms + rd256(16 + lr, c*64 + kk*32 + lg*8));
#pragma unroll
          for (int j = 0; j < 4; ++j){
            s16x8 bb = *(const s16x8*)(Bs + rdA64(w*64 + j*16 + lr, kk*32 + lg*8));
            pa0[j] = MFMA16(a0, bb, pa0[j]);
            pa1[j] = MFMA16(a1, bb, pa1[j]);
          }
        }
      }
#pragma unroll
      for (int j = 0; j < 4; ++j)
#pragma unroll
        for (int r = 0; r < 4; ++r){
          int colp = w*64 + j*16 + lr;
          Pout[(size_t)(grow0 + lg*4 + r)      * 1024 + pn*256 + colp] = f2bf(pa0[j][r]);
          Pout[(size_t)(grow0 + 16 + lg*4 + r) * 1024 + pn*256 + colp] = f2bf(pa1[j][r]);
        }
    }
  } else {
    // ---- readout partial: g[b*256+c] += sum rows ----
    float s0 = 0.f, s1 = 0.f;
#pragma unroll
    for (int rl = 0; rl < 32; rl += 2){
      s0 += Hf[rl * 256 + tid];
      s1 += Hf[(rl + 1) * 256 + tid];
    }
    atomicAdd(&g[tid], s0);
    atomicAdd(&g[256 + tid], s1);
  }
}

// ------------------------------- CSR build ---------------------------------
__global__ void count_kernel(const int* __restrict__ edst, int* __restrict__ counts){
  int e = blockIdx.x * 256 + threadIdx.x;
  if (e < E_EDGES) atomicAdd(&counts[edst[e]], 1);
}
__global__ void scan_kernel(const int* __restrict__ counts, int* __restrict__ row_start,
                            int* __restrict__ cursor){
  __shared__ int sums[1024];
  int t = threadIdx.x;
  int base = t * 8;
  int loc[8]; int s = 0;
#pragma unroll
  for (int i = 0; i < 8; ++i){ loc[i] = s; s += counts[base + i]; }
  sums[t] = s;
  __syncthreads();
  for (int o = 1; o < 1024; o <<= 1){
    int v = sums[t];
    int u = (t >= o) ? sums[t - o] : 0;
    __syncthreads();
    sums[t] = v + u;
    __syncthreads();
  }
  int excl = (t == 0) ? 0 : sums[t - 1];
#pragma unroll
  for (int i = 0; i < 8; ++i){ int v = excl + loc[i]; row_start[base + i] = v; cursor[base + i] = v; }
  if (t == 1023) row_start[NNODES] = sums[1023];
}
__global__ void fill_kernel(const int* __restrict__ edst, const int* __restrict__ esrc,
                            int* __restrict__ cursor, int* __restrict__ csr_eid,
                            int* __restrict__ csr_src){
  int e = blockIdx.x * 256 + threadIdx.x;
  if (e < E_EDGES){
    int pos = atomicAdd(&cursor[edst[e]], 1);
    csr_eid[pos] = e;
    csr_src[pos] = esrc[e];
  }
}

// --------------------------- weight repacking ------------------------------
// BtP [1024][256], BtE [512][64] PRE-SWIZZLED, BtW2 [256][512],
// BtRZ [512][512] (cols r|z, K = W|U), BtHW [256][512] (K = Wh|Uh)
__global__ void prep_weights(const float* __restrict__ W1, const float* __restrict__ W2,
                             const float* __restrict__ Wr, const float* __restrict__ Ur,
                             const float* __restrict__ Wz, const float* __restrict__ Uz,
                             const float* __restrict__ Wh, const float* __restrict__ Uh,
                             short* __restrict__ BtP, short* __restrict__ BtE,
                             short* __restrict__ BtW2, short* __restrict__ BtRZ,
                             short* __restrict__ BtHW)
{
  int id = blockIdx.x * 256 + threadIdx.x;
  if (id < 262144){                       // BtP
    int jj = id >> 8, k = id & 255;
    float v = (jj < 512) ? W1[(size_t)k * 512 + jj] : W1[(size_t)(256 + k) * 512 + (jj - 512)];
    BtP[id] = f2bf(v);
  } else if (id < 294912){                // BtE pre-swizzled
    int i2 = id - 262144; int jj = i2 >> 6, c = i2 & 63;
    BtE[jj * 64 + (c ^ ((jj & 7) << 3))] = f2bf(W1[(size_t)(512 + c) * 512 + jj]);
  } else if (id < 425984){                // BtW2
    int i2 = id - 294912; int n = i2 >> 9, k = i2 & 511;
    BtW2[i2] = f2bf(W2[(size_t)k * 256 + n]);
  } else if (id < 688128){                // BtRZ
    int i2 = id - 425984; int col = i2 >> 9, k = i2 & 511;
    float v;
    if (col < 256) v = (k < 256) ? Wr[(size_t)k * 256 + col] : Ur[(size_t)(k - 256) * 256 + col];
    else { int c2 = col - 256; v = (k < 256) ? Wz[(size_t)k * 256 + c2] : Uz[(size_t)(k - 256) * 256 + c2]; }
    BtRZ[i2] = f2bf(v);
  } else if (id < 819200){                // BtHW
    int i2 = id - 688128; int col = i2 >> 9, k = i2 & 511;
    float v = (k < 256) ? Wh[(size_t)k * 256 + col] : Uh[(size_t)(k - 256) * 256 + col];
    BtHW[i2] = f2bf(v);
  }
}

// -------------------------------- readout ----------------------------------
__global__ __launch_bounds__(256)
void readout2(const float* __restrict__ g, const float* __restrict__ Wo,
              const float* __restrict__ bo, float* __restrict__ out){
  int t = threadIdx.x;
  int b = t >> 7, o = t & 127;
  float s = bo[o];
  for (int c = 0; c < 256; ++c) s += g[b * 256 + c] * Wo[c * 128 + o];
  out[b * 128 + o] = s;
}

// ===========================================================================
extern "C" void kernel_launch(void* const* d_in, const int* in_sizes, int n_in,
                              void* d_out, int out_size, void* d_ws, size_t ws_size,
                              hipStream_t stream)
{
  const float* ef  = (const float*)d_in[0];
  const float* W1  = (const float*)d_in[1];
  const float* b1  = (const float*)d_in[2];
  const float* W2  = (const float*)d_in[3];
  const float* b2  = (const float*)d_in[4];
  const float* Wr  = (const float*)d_in[5];
  const float* Ur  = (const float*)d_in[6];
  const float* br  = (const float*)d_in[7];
  const float* Wz  = (const float*)d_in[8];
  const float* Uz  = (const float*)d_in[9];
  const float* bz  = (const float*)d_in[10];
  const float* Wh  = (const float*)d_in[11];
  const float* Uh  = (const float*)d_in[12];
  const float* bh  = (const float*)d_in[13];
  const float* Wo  = (const float*)d_in[14];
  const float* bo  = (const float*)d_in[15];
  const int* esrc  = (const int*)d_in[16];
  const int* edst  = (const int*)d_in[17];

  char* base = (char*)d_ws;
  size_t off = 0;
  auto alloc = [&](size_t bytes) -> char* {
    off = (off + 255) & ~(size_t)255;
    char* p = base + off;
    off += bytes;
    return p;
  };
  float* h    = (float*)alloc((size_t)NB * 256 * 4);            // 16 MB
  float* m    = (float*)alloc((size_t)NB * 256 * 4);            // 16 MB
  short* P    = (short*)alloc((size_t)NB * 1024 * 2);           // 32 MB
  short* S    = (short*)alloc((size_t)NB * 512 * 2);            // 16 MB
  unsigned char* E1 = (unsigned char*)alloc((size_t)E_EDGES * 2 * MLPH); // 128 MiB
  short* BtP  = (short*)alloc(262144 * 2);
  short* BtE  = (short*)alloc(32768 * 2);
  short* BtW2 = (short*)alloc(131072 * 2);
  short* BtRZ = (short*)alloc(262144 * 2);
  short* BtHW = (short*)alloc(131072 * 2);
  int* counts = (int*)alloc(NNODES * 4);
  int* rs     = (int*)alloc((NNODES + 1) * 4);
  int* cursor = (int*)alloc(NNODES * 4);
  int* ceid   = (int*)alloc(E_EDGES * 4);
  int* csrc   = (int*)alloc(E_EDGES * 4);
  float* g    = (float*)alloc(512 * 4);
  // total ~216 MB < 256 MiB workspace

  dim3 blk(256);

  // ------------------------------- prep ----------------------------------
  hipMemsetAsync(g,  0, 512 * 4, stream);
  hipMemsetAsync(counts, 0, NNODES * 4, stream);
  prep_weights<<<3200, blk, 0, stream>>>(W1, W2, Wr, Ur, Wz, Uz, Wh, Uh,
                                         BtP, BtE, BtW2, BtRZ, BtHW);
  count_kernel<<<512, blk, 0, stream>>>(edst, counts);
  scan_kernel<<<1, 1024, 0, stream>>>(counts, rs, cursor);
  fill_kernel<<<512, blk, 0, stream>>>(edst, esrc, cursor, ceid, csrc);

  // E1 (fp8) computed ONCE — iteration-invariant
  e1_gemm<<<dim3(E_EDGES * 2 / 128, MLPH / 128), blk, 0, stream>>>(
      ef, BtE, E1, b1, ceid);

  // ----------------------------- iterations ------------------------------
  edge_kernel<false><<<NNODES, blk, 0, stream>>>(P, E1, csrc, rs, S);
  node_update<0><<<NB / RB, blk, 0, stream>>>(S, P, m, h, g,
      BtW2, BtRZ, BtHW, BtP, counts, b2, br, bz, bh);

  edge_kernel<true><<<NNODES, blk, 0, stream>>>(P, E1, csrc, rs, S);
  node_update<1><<<NB / RB, blk, 0, stream>>>(S, P, m, h, g,
      BtW2, BtRZ, BtHW, BtP, counts, b2, br, bz, bh);

  edge_kernel<true><<<NNODES, blk, 0, stream>>>(P, E1, csrc, rs, S);
  node_update<2><<<NB / RB, blk, 0, stream>>>(S, P, m, h, g,
      BtW2, BtRZ, BtHW, BtP, counts, b2, br, bz, bh);

  // ------------------------------ readout --------------------------------
  readout2<<<1, blk, 0, stream>>>(g, Wo, bo, (float*)d_out);
}